// Round 2
// baseline (946.373 us; speedup 1.0000x reference)
//
#include <hip/hip_runtime.h>
#include <math.h>

#define N_DST   25000
#define DN      128
#define DE      128
#define DTF     100
#define DKV     356   // 128 + 128 + 100
#define KP      384   // DKV zero-padded to multiple of 32
#define DQ      228
#define DOUT    128
#define LEAKY   0.2f
#define LN_EPS  1e-5f
#define EB      48    // edges per k_edge block (3 x 16 MFMA rows)
#define LDV     136   // LDS stride for V staging tile (bf16 elems, 272B rows)
#define INV2PI  0.15915494309189535f

// ---- workspace layout (bytes) ----
#define OFF_V       0ull            // E*128 bf16 (edge order) = 102,400,000
#define OFF_SCORE   102400000ull    // E*2 f32   (edge order)  =   3,200,000
#define OFF_QN      105600000ull    // 25000*128 f32           =  12,800,000
#define OFF_WS      118400000ull    // swizzled Wk|Wv bf16     =     196,608
#define OFF_WT      118700000ull    // WoutT f32 256x128       =     131,072
#define OFF_CNT     118900000ull    // 25000 i32
#define OFF_OFFS    119000000ull    // 25001 i32
#define OFF_CURSOR  119100004ull    // 25000 i32
#define OFF_ELIST   119200004ull    // E i32
// total ~120.8 MB

typedef __attribute__((ext_vector_type(8))) short short8;
typedef __attribute__((ext_vector_type(4))) float f32x4;

__device__ __forceinline__ unsigned short f2bf(float x) {
    union { float f; unsigned u; } v; v.f = x;
    unsigned r = v.u + 0x7FFFu + ((v.u >> 16) & 1u);
    return (unsigned short)(r >> 16);
}
__device__ __forceinline__ float bf2f(unsigned short u) {
    union { unsigned u; float f; } v; v.u = ((unsigned)u) << 16;
    return v.f;
}
// fast cos: phase error <= ~1e-4 revolutions at |x|<=1e4 — far below bf16 rounding
__device__ __forceinline__ float fastcos(float x) {
    return __builtin_amdgcn_cosf(__builtin_amdgcn_fractf(x * INV2PI));
}

// ---------------------------------------------------------------------------
// WS: swizzled bf16 weight table so a wave's B-frag load is contiguous 1 KB.
// ---------------------------------------------------------------------------
__global__ __launch_bounds__(128) void k_prepw(const float* __restrict__ Wk,
                                               const float* __restrict__ Wv,
                                               unsigned short* __restrict__ WS) {
    const int n = blockIdx.x;       // 0..255
    const float* src = (n < 128) ? &Wk[(size_t)n * DKV] : &Wv[(size_t)(n - 128) * DKV];
    const int c16 = n >> 4, t16 = n & 15;
    for (int k = threadIdx.x; k < KP; k += 128) {
        float v = (k < DKV) ? src[k] : 0.f;
        int kc = k >> 5, qd = (k >> 3) & 3, j = k & 7;
        WS[(size_t)(((kc * 16 + c16) * 64 + qd * 16 + t16) * 8 + j)] = f2bf(v);
    }
}

__global__ __launch_bounds__(128) void k_prepwt(const float* __restrict__ Wout,
                                                float* __restrict__ WT) {
    const int k = blockIdx.x;       // 0..255
    const int j = threadIdx.x;      // 0..127
    WT[k * 128 + j] = Wout[(size_t)j * 256 + k];
}

// ---------------------------------------------------------------------------
// q_nodes fp32: 256 thr = (col j, k-half kh). Wq half-row in regs, 16 rows/blk.
// ---------------------------------------------------------------------------
__global__ __launch_bounds__(256) void k_qnodes(const float* __restrict__ h,
                                                const float* __restrict__ Wq,
                                                const float* __restrict__ bq,
                                                const float* __restrict__ b_t,
                                                float* __restrict__ qn) {
    __shared__ float hrows[16 * 128];
    __shared__ float part[16 * 128];
    const int tid = threadIdx.x;
    const int j  = tid & 127;
    const int kh = tid >> 7;

    float wq[64];
    #pragma unroll
    for (int k = 0; k < 64; k += 4) {
        float4 w = *(const float4*)&Wq[j * DQ + kh * 64 + k];
        wq[k] = w.x; wq[k + 1] = w.y; wq[k + 2] = w.z; wq[k + 3] = w.w;
    }
    float cq = 0.f;
    if (kh == 0) {
        cq = bq[j];
        for (int k = 0; k < DTF; ++k)
            cq += Wq[j * DQ + 128 + k] * fastcos(b_t[k]);
    }

    const int r0 = blockIdx.x * 16;
    for (int u = tid; u < 512; u += 256) {          // 512 float4s = 16 rows
        int rr = u >> 5, q = u & 31;
        int r = r0 + rr;
        float4 v = make_float4(0.f, 0.f, 0.f, 0.f);
        if (r < N_DST) v = *(const float4*)&h[(size_t)r * DN + q * 4];
        *(float4*)&hrows[rr * 128 + q * 4] = v;
    }
    __syncthreads();

    float acc[16];
    #pragma unroll
    for (int rr = 0; rr < 16; ++rr) acc[rr] = 0.f;
    #pragma unroll
    for (int k4 = 0; k4 < 64; k4 += 4) {
        float w0 = wq[k4], w1 = wq[k4 + 1], w2 = wq[k4 + 2], w3 = wq[k4 + 3];
        #pragma unroll
        for (int rr = 0; rr < 16; ++rr) {
            float4 hv = *(float4*)&hrows[rr * 128 + kh * 64 + k4];
            acc[rr] += w0 * hv.x + w1 * hv.y + w2 * hv.z + w3 * hv.w;
        }
    }
    if (kh == 1) {
        #pragma unroll
        for (int rr = 0; rr < 16; ++rr) part[rr * 128 + j] = acc[rr];
    }
    __syncthreads();
    if (kh == 0) {
        #pragma unroll
        for (int rr = 0; rr < 16; ++rr) {
            int r = r0 + rr;
            if (r < N_DST)
                qn[(size_t)r * DOUT + j] = acc[rr] + part[rr * 128 + j] + cq;
        }
    }
}

// ---------------------------------------------------------------------------
// CSR build (elist = edge ids in CSR order)
// ---------------------------------------------------------------------------
__global__ void k_hist(const int* __restrict__ dst, int* __restrict__ cnt, int E) {
    int i = blockIdx.x * 256 + threadIdx.x;
    if (i < E) atomicAdd(&cnt[dst[i]], 1);
}

__global__ __launch_bounds__(256) void k_scan(const int* __restrict__ cnt,
                                              int* __restrict__ offs,
                                              int* __restrict__ cursor) {
    __shared__ int totals[256];
    __shared__ int bases[257];
    const int t = threadIdx.x;
    const int STRIP = (N_DST + 255) / 256;
    int s = 0;
    for (int i = 0; i < STRIP; ++i) {
        int idx = t * STRIP + i;
        if (idx < N_DST) s += cnt[idx];
    }
    totals[t] = s;
    __syncthreads();
    if (t == 0) {
        int run = 0;
        for (int i = 0; i < 256; ++i) { bases[i] = run; run += totals[i]; }
        bases[256] = run;
    }
    __syncthreads();
    int run = bases[t];
    for (int i = 0; i < STRIP; ++i) {
        int idx = t * STRIP + i;
        if (idx < N_DST) {
            offs[idx] = run;
            cursor[idx] = run;
            run += cnt[idx];
        }
    }
    if (t == 0) offs[N_DST] = bases[256];
}

__global__ void k_scatter(const int* __restrict__ dst, int* __restrict__ cursor,
                          int* __restrict__ elist, int E) {
    int i = blockIdx.x * 256 + threadIdx.x;
    if (i < E) {
        int d = dst[i];
        int pos = atomicAdd(&cursor[d], 1);
        elist[pos] = i;
    }
}

// ---------------------------------------------------------------------------
// Edge K/V projection via bf16 MFMA + attention scores.
// v3: 48-edge tiles + two-phase K staging (A tile 48x192 bf16, XOR-swizzled)
// -> LDS 19KB/block, target 4-5 blocks/CU (was 3) for latency hiding.
// K layout (matches WS): cols [0,128)=h, [128,256)=f, [256,356)=time, pad.
// Phase 0 stages cols [0,192), phase 1 stages cols [192,384).
// ---------------------------------------------------------------------------
__global__ __launch_bounds__(256, 4) void k_edge(const float* __restrict__ h,
                                                 const float* __restrict__ f,
                                                 const float* __restrict__ dtv,
                                                 const int* __restrict__ src_idx,
                                                 const int* __restrict__ dst_idx,
                                                 const float* __restrict__ w_t,
                                                 const float* __restrict__ b_t,
                                                 const unsigned short* __restrict__ WS,
                                                 const float* __restrict__ bk,
                                                 const float* __restrict__ bv,
                                                 const float* __restrict__ qn,
                                                 unsigned short* __restrict__ Vout,
                                                 float* __restrict__ score,
                                                 int E) {
    __shared__ unsigned short At[EB * 192];   // 18432 B, XOR-swizzled phase tile
    __shared__ int   sidx[EB];
    __shared__ int   didx[EB];
    __shared__ float sdt[EB];

    const int tid = threadIdx.x;
    const int e0  = blockIdx.x * EB;

    if (tid < EB) {
        int ge = min(e0 + tid, E - 1);
        sidx[tid] = src_idx[ge];
        didx[tid] = dst_idx[ge];
        sdt[tid]  = dtv[ge];
    }
    __syncthreads();

    const int lane = tid & 63;
    const int w    = tid >> 6;
    const int t16  = lane & 15;
    const int qd   = lane >> 4;
    const int w4   = w * 4;

    f32x4 acc[3][4];
    #pragma unroll
    for (int r = 0; r < 3; ++r)
        #pragma unroll
        for (int c = 0; c < 4; ++c)
            acc[r][c] = (f32x4){0.f, 0.f, 0.f, 0.f};

    // ---- two K-phases: stage 192 cols, run 6 kc chunks each ----
    #pragma unroll
    for (int p = 0; p < 2; ++p) {
        // stage: 48 edges x 24 16B-chunks = 1152 chunks, 8 bf16 cols each
        #pragma unroll
        for (int k = 0; k < 5; ++k) {
            int u = tid + k * 256;
            if (u < EB * 24) {
                int e  = u / 24;
                int j  = u - e * 24;
                int c0 = p * 192 + j * 8;
                int ge = min(e0 + e, E - 1);
                float v[8];
                if (c0 < 256) {
                    const float* src = (c0 < 128)
                        ? &h[(size_t)sidx[e] * DN + c0]
                        : &f[(size_t)ge * DE + (c0 - 128)];
                    float4 x = *(const float4*)src;
                    float4 y = *(const float4*)(src + 4);
                    v[0] = x.x; v[1] = x.y; v[2] = x.z; v[3] = x.w;
                    v[4] = y.x; v[5] = y.y; v[6] = y.z; v[7] = y.w;
                } else {
                    const float dte = sdt[e];
                    const int t0 = c0 - 256;
                    #pragma unroll
                    for (int i2 = 0; i2 < 8; ++i2) {
                        int c = t0 + i2;
                        v[i2] = (c < DTF) ? fastcos(dte * w_t[c] + b_t[c]) : 0.f;
                    }
                }
                short8 pk;
                #pragma unroll
                for (int i2 = 0; i2 < 8; ++i2) pk[i2] = (short)f2bf(v[i2]);
                *(short8*)&At[(unsigned)((e * 192 + j * 8) ^ ((e & 7) << 3))] = pk;
            }
        }
        __syncthreads();

        #pragma unroll
        for (int kcl = 0; kcl < 6; ++kcl) {
            const int kg = p * 6 + kcl;
            short8 a[3], b[4];
            #pragma unroll
            for (int r = 0; r < 3; ++r)
                a[r] = *(const short8*)&At[(unsigned)(
                    (((r * 16 + t16) * 192) + kcl * 32 + qd * 8) ^ ((t16 & 7) << 3))];
            #pragma unroll
            for (int c = 0; c < 4; ++c)
                b[c] = *(const short8*)(WS + (size_t)((kg * 16 + w4 + c) * 64 + lane) * 8);
            #pragma unroll
            for (int r = 0; r < 3; ++r)
                #pragma unroll
                for (int c = 0; c < 4; ++c)
                    acc[r][c] = __builtin_amdgcn_mfma_f32_16x16x32_bf16(a[r], b[c], acc[r][c], 0, 0, 0);
        }
        __syncthreads();   // phase0: before restage; phase1: before V-stage reuse
    }

    // ---- epilogue (C/D: outcol = c*16+t16, edge = r*16 + qd*4 + i) ----
    if (w >= 2) {
        const int half = w - 2;            // 0: V cols 0..63, 1: V cols 64..127
        const int vc0  = half * 64;
        float bvv[4];
        #pragma unroll
        for (int c = 0; c < 4; ++c) bvv[c] = bv[vc0 + c * 16 + t16];

        // scatter acc into the staging tile (reuses At; disjoint col-halves
        // per wave; only same-wave lanes read it back)
        #pragma unroll
        for (int r = 0; r < 3; ++r) {
            #pragma unroll
            for (int i = 0; i < 4; ++i) {
                const int el = r * 16 + qd * 4 + i;
                #pragma unroll
                for (int c = 0; c < 4; ++c)
                    At[el * LDV + vc0 + c * 16 + t16] = f2bf(acc[r][c][i] + bvv[c]);
            }
        }
        asm volatile("s_waitcnt lgkmcnt(0)" ::: "memory");

        // coalesced store: 8 lanes cover one row's 128B half
        const int row0 = lane >> 3;        // 0..7
        const int ch   = lane & 7;         // 16B chunk within the half-row
        #pragma unroll
        for (int it = 0; it < 6; ++it) {
            const int el = row0 + it * 8;
            const int ge = e0 + el;
            short8 vv = *(const short8*)&At[el * LDV + vc0 + ch * 8];
            if (ge < E)
                *(short8*)&Vout[(size_t)ge * DOUT + vc0 + ch * 8] = vv;
        }
    } else {
        float bkc[4];
        #pragma unroll
        for (int c = 0; c < 4; ++c)
            bkc[c] = bk[w * 64 + c * 16 + t16];
        #pragma unroll
        for (int r = 0; r < 3; ++r) {
            // batch all 16 qn loads for this r-row before the dot/shfl chain
            float qv[4][4];
            #pragma unroll
            for (int i = 0; i < 4; ++i) {
                const int d = didx[r * 16 + qd * 4 + i];
                const float* qrow = &qn[(size_t)d * DOUT + w * 64 + t16];
                qv[i][0] = qrow[0];
                qv[i][1] = qrow[16];
                qv[i][2] = qrow[32];
                qv[i][3] = qrow[48];
            }
            #pragma unroll
            for (int i = 0; i < 4; ++i) {
                float p = (acc[r][0][i] + bkc[0]) * qv[i][0]
                        + (acc[r][1][i] + bkc[1]) * qv[i][1]
                        + (acc[r][2][i] + bkc[2]) * qv[i][2]
                        + (acc[r][3][i] + bkc[3]) * qv[i][3];
                p += __shfl_xor(p, 1);
                p += __shfl_xor(p, 2);
                p += __shfl_xor(p, 4);
                p += __shfl_xor(p, 8);
                if (t16 == 0) {
                    const int ge = e0 + r * 16 + qd * 4 + i;
                    if (ge < E) {
                        float sc = (p >= 0.f) ? p : LEAKY * p;
                        score[(size_t)ge * 2 + w] = sc;
                    }
                }
            }
        }
    }
}

// ---------------------------------------------------------------------------
// Per-dst: softmax + weighted V sum (gather via elist) + out-proj + ReLU + LN.
// 512 threads = 16 dsts x 32 threads (4 cols each). WoutT staged via LDS.
// ---------------------------------------------------------------------------
__global__ __launch_bounds__(512) void k_dst(const unsigned short* __restrict__ V,
                                             const float* __restrict__ score,
                                             const int* __restrict__ offs,
                                             const int* __restrict__ elist,
                                             const float* __restrict__ h,
                                             const float* __restrict__ WT,
                                             const float* __restrict__ bout,
                                             const float* __restrict__ ln_w,
                                             const float* __restrict__ ln_b,
                                             float* __restrict__ out) {
    const int tid = threadIdx.x;
    const int s   = tid >> 5;        // sub 0..15
    const int t32 = tid & 31;
    const int d   = blockIdx.x * 16 + s;
    const bool valid = d < N_DST;
    const int beg = valid ? offs[d] : 0;
    const int end = valid ? offs[d + 1] : 0;

    __shared__ float inc[16][256];
    __shared__ float wchunk[64 * 128];

    // pass A: per-head max
    float m0 = -1e30f, m1 = -1e30f;
    for (int i = beg + t32; i < end; i += 32) {
        int e = elist[i];
        float2 sc = *(const float2*)&score[(size_t)e * 2];
        m0 = fmaxf(m0, sc.x);
        m1 = fmaxf(m1, sc.y);
    }
    #pragma unroll
    for (int o = 1; o < 32; o <<= 1) {
        m0 = fmaxf(m0, __shfl_xor(m0, o));
        m1 = fmaxf(m1, __shfl_xor(m1, o));
    }
    const int   hd = t32 >> 4;
    const float mh = hd ? m1 : m0;

    // pass B: exp-weighted V accumulation (V rows gathered, 256B granules)
    float a0 = 0.f, a1 = 0.f, a2 = 0.f, a3 = 0.f, l = 0.f;
    int i = beg;
    for (; i + 1 < end; i += 2) {
        int ea = elist[i], eb = elist[i + 1];
        float s0 = score[(size_t)ea * 2 + hd];
        float s1 = score[(size_t)eb * 2 + hd];
        ushort4 v0 = *(const ushort4*)&V[(size_t)ea * DOUT + t32 * 4];
        ushort4 v1 = *(const ushort4*)&V[(size_t)eb * DOUT + t32 * 4];
        float w0 = __expf(s0 - mh);
        float w1 = __expf(s1 - mh);
        l += w0 + w1;
        a0 += w0 * bf2f(v0.x) + w1 * bf2f(v1.x);
        a1 += w0 * bf2f(v0.y) + w1 * bf2f(v1.y);
        a2 += w0 * bf2f(v0.z) + w1 * bf2f(v1.z);
        a3 += w0 * bf2f(v0.w) + w1 * bf2f(v1.w);
    }
    if (i < end) {
        int ea = elist[i];
        float s0 = score[(size_t)ea * 2 + hd];
        ushort4 v0 = *(const ushort4*)&V[(size_t)ea * DOUT + t32 * 4];
        float w0 = __expf(s0 - mh);
        l += w0;
        a0 += w0 * bf2f(v0.x);
        a1 += w0 * bf2f(v0.y);
        a2 += w0 * bf2f(v0.z);
        a3 += w0 * bf2f(v0.w);
    }
    float inv = (l > 0.f) ? (1.f / l) : 0.f;
    inc[s][t32 * 4 + 0] = a0 * inv;
    inc[s][t32 * 4 + 1] = a1 * inv;
    inc[s][t32 * 4 + 2] = a2 * inv;
    inc[s][t32 * 4 + 3] = a3 * inv;
    {
        float4 hh = make_float4(0.f, 0.f, 0.f, 0.f);
        if (valid) hh = *(const float4*)&h[(size_t)d * DN + t32 * 4];
        *(float4*)&inc[s][128 + t32 * 4] = hh;
    }

    // out-proj: r4 = bout + WoutT . inc, staged in 4 x 32KB LDS chunks
    float4 r4 = *(const float4*)&bout[t32 * 4];
    #pragma unroll 1
    for (int ch = 0; ch < 4; ++ch) {
        __syncthreads();
        for (int u = tid; u < 2048; u += 512)
            *(float4*)&wchunk[u * 4] = *(const float4*)&WT[(size_t)ch * 8192 + u * 4];
        __syncthreads();
        #pragma unroll 4
        for (int kk = 0; kk < 64; ++kk) {
            float ic = inc[s][ch * 64 + kk];
            float4 w4 = *(float4*)&wchunk[kk * 128 + t32 * 4];
            r4.x += w4.x * ic;
            r4.y += w4.y * ic;
            r4.z += w4.z * ic;
            r4.w += w4.w * ic;
        }
    }
    r4.x = fmaxf(r4.x, 0.f);
    r4.y = fmaxf(r4.y, 0.f);
    r4.z = fmaxf(r4.z, 0.f);
    r4.w = fmaxf(r4.w, 0.f);

    // LayerNorm over the dst's 128 cols (32 lanes x 4)
    float s1 = r4.x + r4.y + r4.z + r4.w;
    float s2 = r4.x * r4.x + r4.y * r4.y + r4.z * r4.z + r4.w * r4.w;
    #pragma unroll
    for (int o = 1; o < 32; o <<= 1) {
        s1 += __shfl_xor(s1, o);
        s2 += __shfl_xor(s2, o);
    }
    float mu  = s1 * (1.f / 128.f);
    float var = s2 * (1.f / 128.f) - mu * mu;
    float rsd = rsqrtf(var + LN_EPS);
    if (valid) {
        float4 lw = *(const float4*)&ln_w[t32 * 4];
        float4 lb = *(const float4*)&ln_b[t32 * 4];
        float4 o4;
        o4.x = (r4.x - mu) * rsd * lw.x + lb.x;
        o4.y = (r4.y - mu) * rsd * lw.y + lb.y;
        o4.z = (r4.z - mu) * rsd * lw.z + lb.z;
        o4.w = (r4.w - mu) * rsd * lw.w + lb.w;
        *(float4*)&out[(size_t)d * DOUT + t32 * 4] = o4;
    }
}

// ---------------------------------------------------------------------------
extern "C" void kernel_launch(void* const* d_in, const int* in_sizes, int n_in,
                              void* d_out, int out_size, void* d_ws, size_t ws_size,
                              hipStream_t stream) {
    const float* h       = (const float*)d_in[0];
    const float* f       = (const float*)d_in[1];
    const float* dt      = (const float*)d_in[2];
    const int*   src_idx = (const int*)d_in[3];
    const int*   dst_idx = (const int*)d_in[4];
    const float* w_t     = (const float*)d_in[5];
    const float* b_t     = (const float*)d_in[6];
    const float* Wq      = (const float*)d_in[7];
    const float* bq      = (const float*)d_in[8];
    const float* Wk      = (const float*)d_in[9];
    const float* bk      = (const float*)d_in[10];
    const float* Wv      = (const float*)d_in[11];
    const float* bv      = (const float*)d_in[12];
    const float* Wout    = (const float*)d_in[13];
    const float* bout    = (const float*)d_in[14];
    const float* ln_w    = (const float*)d_in[15];
    const float* ln_b    = (const float*)d_in[16];
    float*       out     = (float*)d_out;

    const int E = in_sizes[2];

    char* ws = (char*)d_ws;
    unsigned short* V  = (unsigned short*)(ws + OFF_V);
    float* score       = (float*)(ws + OFF_SCORE);
    float* qn          = (float*)(ws + OFF_QN);
    unsigned short* WS = (unsigned short*)(ws + OFF_WS);
    float* WT          = (float*)(ws + OFF_WT);
    int*   cnt         = (int*)(ws + OFF_CNT);
    int*   offs        = (int*)(ws + OFF_OFFS);
    int*   cursor      = (int*)(ws + OFF_CURSOR);
    int*   elist       = (int*)(ws + OFF_ELIST);

    hipMemsetAsync(cnt, 0, N_DST * sizeof(int), stream);

    k_prepw<<<256, 128, 0, stream>>>(Wk, Wv, WS);
    k_prepwt<<<256, 128, 0, stream>>>(Wout, WT);
    k_qnodes<<<(N_DST + 15) / 16, 256, 0, stream>>>(h, Wq, bq, b_t, qn);
    k_hist<<<(E + 255) / 256, 256, 0, stream>>>(dst_idx, cnt, E);
    k_scan<<<1, 256, 0, stream>>>(cnt, offs, cursor);
    k_scatter<<<(E + 255) / 256, 256, 0, stream>>>(dst_idx, cursor, elist, E);
    k_edge<<<(E + EB - 1) / EB, 256, 0, stream>>>(h, f, dt, src_idx, dst_idx,
                                                  w_t, b_t, WS, bk, bv, qn, V, score, E);
    k_dst<<<(N_DST + 15) / 16, 512, 0, stream>>>(V, score, offs, elist, h, WT, bout,
                                                 ln_w, ln_b, out);
}

// Round 3
// 738.142 us; speedup vs baseline: 1.2821x; 1.2821x over previous
//
#include <hip/hip_runtime.h>
#include <math.h>

#define N_DST   25000
#define DN      128
#define DE      128
#define DTF     100
#define DKV     356   // 128 + 128 + 100
#define KP      384   // DKV zero-padded to multiple of 32
#define DQ      228
#define DOUT    128
#define LEAKY   0.2f
#define LN_EPS  1e-5f
#define LDA     392   // LDS stride for A tile (bf16 elems)
#define LDV     136   // LDS stride for V staging tile (bf16 elems, 272B rows)
#define INV2PI  0.15915494309189535f

// ---- workspace layout (bytes) ----
#define OFF_V       0ull            // E*128 bf16 (CSR order) = 102,400,000
#define OFF_SCORE   102400000ull    // E*2 f32   (CSR order)  =   3,200,000
#define OFF_QN      105600000ull    // 25000*128 f32           =  12,800,000
#define OFF_WS      118400000ull    // swizzled Wk|Wv bf16     =     196,608
#define OFF_WT      118700000ull    // WoutT f32 256x128       =     131,072
#define OFF_CNT     118900000ull    // 25000 i32
#define OFF_OFFS    119000000ull    // 25001 i32
#define OFF_CURSOR  119100004ull    // 25000 i32
#define OFF_EPOS    119200004ull    // E i32 (edge -> CSR slot)
// total ~120.8 MB

typedef __attribute__((ext_vector_type(8))) short short8;
typedef __attribute__((ext_vector_type(4))) float f32x4;

__device__ __forceinline__ unsigned short f2bf(float x) {
    union { float f; unsigned u; } v; v.f = x;
    unsigned r = v.u + 0x7FFFu + ((v.u >> 16) & 1u);
    return (unsigned short)(r >> 16);
}
__device__ __forceinline__ float bf2f(unsigned short u) {
    union { unsigned u; float f; } v; v.u = ((unsigned)u) << 16;
    return v.f;
}
// fast cos: phase error <= ~1e-4 revolutions at |x|<=1e4 — far below bf16 rounding
__device__ __forceinline__ float fastcos(float x) {
    return __builtin_amdgcn_cosf(__builtin_amdgcn_fractf(x * INV2PI));
}

// ---------------------------------------------------------------------------
// WS: swizzled bf16 weight table so a wave's B-frag load is contiguous 1 KB.
// ---------------------------------------------------------------------------
__global__ __launch_bounds__(128) void k_prepw(const float* __restrict__ Wk,
                                               const float* __restrict__ Wv,
                                               unsigned short* __restrict__ WS) {
    const int n = blockIdx.x;       // 0..255
    const float* src = (n < 128) ? &Wk[(size_t)n * DKV] : &Wv[(size_t)(n - 128) * DKV];
    const int c16 = n >> 4, t16 = n & 15;
    for (int k = threadIdx.x; k < KP; k += 128) {
        float v = (k < DKV) ? src[k] : 0.f;
        int kc = k >> 5, qd = (k >> 3) & 3, j = k & 7;
        WS[(size_t)(((kc * 16 + c16) * 64 + qd * 16 + t16) * 8 + j)] = f2bf(v);
    }
}

__global__ __launch_bounds__(128) void k_prepwt(const float* __restrict__ Wout,
                                                float* __restrict__ WT) {
    const int k = blockIdx.x;       // 0..255
    const int j = threadIdx.x;      // 0..127
    WT[k * 128 + j] = Wout[(size_t)j * 256 + k];
}

// ---------------------------------------------------------------------------
// q_nodes fp32: 256 thr = (col j, k-half kh). Wq half-row in regs, 16 rows/blk.
// ---------------------------------------------------------------------------
__global__ __launch_bounds__(256) void k_qnodes(const float* __restrict__ h,
                                                const float* __restrict__ Wq,
                                                const float* __restrict__ bq,
                                                const float* __restrict__ b_t,
                                                float* __restrict__ qn) {
    __shared__ float hrows[16 * 128];
    __shared__ float part[16 * 128];
    const int tid = threadIdx.x;
    const int j  = tid & 127;
    const int kh = tid >> 7;

    float wq[64];
    #pragma unroll
    for (int k = 0; k < 64; k += 4) {
        float4 w = *(const float4*)&Wq[j * DQ + kh * 64 + k];
        wq[k] = w.x; wq[k + 1] = w.y; wq[k + 2] = w.z; wq[k + 3] = w.w;
    }
    float cq = 0.f;
    if (kh == 0) {
        cq = bq[j];
        #pragma unroll
        for (int k = 0; k < DTF; k += 4) {
            float4 wv = *(const float4*)&Wq[j * DQ + 128 + k];
            float4 bt = *(const float4*)&b_t[k];
            cq += wv.x * fastcos(bt.x) + wv.y * fastcos(bt.y)
                + wv.z * fastcos(bt.z) + wv.w * fastcos(bt.w);
        }
    }

    const int r0 = blockIdx.x * 16;
    for (int u = tid; u < 512; u += 256) {          // 512 float4s = 16 rows
        int rr = u >> 5, q = u & 31;
        int r = r0 + rr;
        float4 v = make_float4(0.f, 0.f, 0.f, 0.f);
        if (r < N_DST) v = *(const float4*)&h[(size_t)r * DN + q * 4];
        *(float4*)&hrows[rr * 128 + q * 4] = v;
    }
    __syncthreads();

    float acc[16];
    #pragma unroll
    for (int rr = 0; rr < 16; ++rr) acc[rr] = 0.f;
    #pragma unroll
    for (int k4 = 0; k4 < 64; k4 += 4) {
        float w0 = wq[k4], w1 = wq[k4 + 1], w2 = wq[k4 + 2], w3 = wq[k4 + 3];
        #pragma unroll
        for (int rr = 0; rr < 16; ++rr) {
            float4 hv = *(float4*)&hrows[rr * 128 + kh * 64 + k4];
            acc[rr] += w0 * hv.x + w1 * hv.y + w2 * hv.z + w3 * hv.w;
        }
    }
    if (kh == 1) {
        #pragma unroll
        for (int rr = 0; rr < 16; ++rr) part[rr * 128 + j] = acc[rr];
    }
    __syncthreads();
    if (kh == 0) {
        #pragma unroll
        for (int rr = 0; rr < 16; ++rr) {
            int r = r0 + rr;
            if (r < N_DST)
                qn[(size_t)r * DOUT + j] = acc[rr] + part[rr * 128 + j] + cq;
        }
    }
}

// ---------------------------------------------------------------------------
// CSR build (epos = edge id -> CSR slot; producers write in CSR order)
// ---------------------------------------------------------------------------
__global__ void k_hist(const int* __restrict__ dst, int* __restrict__ cnt, int E) {
    int i = blockIdx.x * 256 + threadIdx.x;
    if (i < E) atomicAdd(&cnt[dst[i]], 1);
}

__global__ __launch_bounds__(256) void k_scan(const int* __restrict__ cnt,
                                              int* __restrict__ offs,
                                              int* __restrict__ cursor) {
    __shared__ int totals[256];
    __shared__ int bases[257];
    const int t = threadIdx.x;
    const int STRIP = (N_DST + 255) / 256;
    int s = 0;
    for (int i = 0; i < STRIP; ++i) {
        int idx = t * STRIP + i;
        if (idx < N_DST) s += cnt[idx];
    }
    totals[t] = s;
    __syncthreads();
    if (t == 0) {
        int run = 0;
        for (int i = 0; i < 256; ++i) { bases[i] = run; run += totals[i]; }
        bases[256] = run;
    }
    __syncthreads();
    int run = bases[t];
    for (int i = 0; i < STRIP; ++i) {
        int idx = t * STRIP + i;
        if (idx < N_DST) {
            offs[idx] = run;
            cursor[idx] = run;
            run += cnt[idx];
        }
    }
    if (t == 0) offs[N_DST] = bases[256];
}

__global__ void k_scatter(const int* __restrict__ dst, int* __restrict__ cursor,
                          int* __restrict__ epos, int E) {
    int i = blockIdx.x * 256 + threadIdx.x;
    if (i < E) {
        int d = dst[i];
        epos[i] = atomicAdd(&cursor[d], 1);    // coalesced write, edge order
    }
}

// ---------------------------------------------------------------------------
// Edge K/V projection via bf16 MFMA + attention scores. (R0 structure: 64-edge
// tiles, single-phase 16-deep staging, reg double-buffered MFMA.) Outputs now
// land at CSR slot epos[e] so the consumer streams them contiguously per dst.
// ---------------------------------------------------------------------------
__global__ __launch_bounds__(256, 3) void k_edge(const float* __restrict__ h,
                                                 const float* __restrict__ f,
                                                 const float* __restrict__ dtv,
                                                 const int* __restrict__ src_idx,
                                                 const int* __restrict__ dst_idx,
                                                 const int* __restrict__ epos,
                                                 const float* __restrict__ w_t,
                                                 const float* __restrict__ b_t,
                                                 const unsigned short* __restrict__ WS,
                                                 const float* __restrict__ bk,
                                                 const float* __restrict__ bv,
                                                 const float* __restrict__ qn,
                                                 unsigned short* __restrict__ Vout,
                                                 float* __restrict__ score,
                                                 int E) {
    __shared__ unsigned short At[64 * LDA];
    __shared__ int sidx[64];
    __shared__ int didx[64];
    __shared__ int spos[64];

    const int tid = threadIdx.x;
    const int e0  = blockIdx.x * 64;

    if (tid < 64) {
        int ge = min(e0 + tid, E - 1);
        sidx[tid] = src_idx[ge];
        didx[tid] = dst_idx[ge];
        spos[tid] = epos[ge];
    }
    __syncthreads();

    // ---- stage A: 16-deep batched loads (h|f), then time features ----
    {
        const int e  = tid >> 2;          // 0..63
        const int qb = tid & 3;
        const int ge = min(e0 + e, E - 1);
        const int s  = sidx[e];
        const float dte = dtv[ge];
        const float* hb = &h[(size_t)s * DN];
        const float* fb = &f[(size_t)ge * DE];
        float4 buf[16];

        #pragma unroll
        for (int it = 0; it < 8; ++it) buf[it]     = *(const float4*)&hb[qb * 4 + it * 16];
        #pragma unroll
        for (int it = 0; it < 8; ++it) buf[8 + it] = *(const float4*)&fb[qb * 4 + it * 16];
        #pragma unroll
        for (int it = 0; it < 16; ++it) {
            int c = (it < 8) ? (qb * 4 + it * 16) : (128 + qb * 4 + (it - 8) * 16);
            union { unsigned short us[4]; uint2 u2; } pk;
            pk.us[0] = f2bf(buf[it].x); pk.us[1] = f2bf(buf[it].y);
            pk.us[2] = f2bf(buf[it].z); pk.us[3] = f2bf(buf[it].w);
            *(uint2*)&At[e * LDA + c] = pk.u2;
        }
        #pragma unroll
        for (int it = 0; it < 8; ++it) {
            int t0 = qb * 4 + it * 16;         // 0..124, multiple of 4
            float4 v = make_float4(0.f, 0.f, 0.f, 0.f);
            if (t0 < DTF) {
                float4 wt = *(const float4*)&w_t[t0];
                float4 bt = *(const float4*)&b_t[t0];
                v.x = fastcos(dte * wt.x + bt.x);
                v.y = fastcos(dte * wt.y + bt.y);
                v.z = fastcos(dte * wt.z + bt.z);
                v.w = fastcos(dte * wt.w + bt.w);
            }
            union { unsigned short us[4]; uint2 u2; } pk;
            pk.us[0] = f2bf(v.x); pk.us[1] = f2bf(v.y);
            pk.us[2] = f2bf(v.z); pk.us[3] = f2bf(v.w);
            *(uint2*)&At[e * LDA + 256 + t0] = pk.u2;
        }
    }
    __syncthreads();

    // ---- MFMA main loop, A/B register double-buffered ----
    const int lane = tid & 63;
    const int w    = tid >> 6;
    const int t16  = lane & 15;
    const int qd   = lane >> 4;
    const int w4   = w * 4;

    f32x4 acc[4][4];
    #pragma unroll
    for (int r = 0; r < 4; ++r)
        #pragma unroll
        for (int c = 0; c < 4; ++c)
            acc[r][c] = (f32x4){0.f, 0.f, 0.f, 0.f};

    short8 aC[4], aN[4], bC[4], bN[4];
    #pragma unroll
    for (int r = 0; r < 4; ++r)
        aC[r] = *(const short8*)&At[(r * 16 + t16) * LDA + qd * 8];
    #pragma unroll
    for (int c = 0; c < 4; ++c)
        bC[c] = *(const short8*)(WS + (size_t)((w4 + c) * 64 + lane) * 8);

    #pragma unroll 1
    for (int kc = 0; kc < 12; kc += 2) {
        #pragma unroll
        for (int r = 0; r < 4; ++r)
            aN[r] = *(const short8*)&At[(r * 16 + t16) * LDA + (kc + 1) * 32 + qd * 8];
        #pragma unroll
        for (int c = 0; c < 4; ++c)
            bN[c] = *(const short8*)(WS + (size_t)(((kc + 1) * 16 + w4 + c) * 64 + lane) * 8);
        #pragma unroll
        for (int r = 0; r < 4; ++r)
            #pragma unroll
            for (int c = 0; c < 4; ++c)
                acc[r][c] = __builtin_amdgcn_mfma_f32_16x16x32_bf16(aC[r], bC[c], acc[r][c], 0, 0, 0);
        if (kc + 2 < 12) {
            #pragma unroll
            for (int r = 0; r < 4; ++r)
                aC[r] = *(const short8*)&At[(r * 16 + t16) * LDA + (kc + 2) * 32 + qd * 8];
            #pragma unroll
            for (int c = 0; c < 4; ++c)
                bC[c] = *(const short8*)(WS + (size_t)(((kc + 2) * 16 + w4 + c) * 64 + lane) * 8);
        }
        #pragma unroll
        for (int r = 0; r < 4; ++r)
            #pragma unroll
            for (int c = 0; c < 4; ++c)
                acc[r][c] = __builtin_amdgcn_mfma_f32_16x16x32_bf16(aN[r], bN[c], acc[r][c], 0, 0, 0);
    }

    // All waves done reading At — safe to reuse it as the V staging tile.
    __syncthreads();

    // ---- epilogue (C/D: outcol = c*16+t16, edge = r*16 + qd*4 + i) ----
    if (w >= 2) {
        const int half = w - 2;            // 0: V cols 0..63, 1: V cols 64..127
        const int vc0  = half * 64;
        float bvv[4];
        #pragma unroll
        for (int c = 0; c < 4; ++c) bvv[c] = bv[vc0 + c * 16 + t16];

        // scatter acc into the staging tile (disjoint col-halves per wave;
        // only same-wave lanes read it back → lgkmcnt-only ordering)
        #pragma unroll
        for (int r = 0; r < 4; ++r) {
            #pragma unroll
            for (int i = 0; i < 4; ++i) {
                const int el = r * 16 + qd * 4 + i;
                #pragma unroll
                for (int c = 0; c < 4; ++c)
                    At[el * LDV + vc0 + c * 16 + t16] = f2bf(acc[r][c][i] + bvv[c]);
            }
        }
        asm volatile("s_waitcnt lgkmcnt(0)" ::: "memory");

        // store: 8 lanes cover one row's 128B half; dest row = CSR slot.
        const int row0 = lane >> 3;        // 0..7
        const int ch   = lane & 7;         // 16B chunk within the half-row
        #pragma unroll
        for (int it = 0; it < 8; ++it) {
            const int el = row0 + it * 8;
            const int ge = e0 + el;
            short8 vv = *(const short8*)&At[el * LDV + vc0 + ch * 8];
            if (ge < E)
                *(short8*)&Vout[(size_t)spos[el] * DOUT + vc0 + ch * 8] = vv;
        }
    } else {
        float bkc[4];
        #pragma unroll
        for (int c = 0; c < 4; ++c)
            bkc[c] = bk[w * 64 + c * 16 + t16];
        #pragma unroll
        for (int r = 0; r < 4; ++r) {
            // batch all 16 qn loads for this r-row before the dot/shfl chain
            float qv[4][4];
            #pragma unroll
            for (int i = 0; i < 4; ++i) {
                const int d = didx[r * 16 + qd * 4 + i];
                const float* qrow = &qn[(size_t)d * DOUT + w * 64 + t16];
                qv[i][0] = qrow[0];
                qv[i][1] = qrow[16];
                qv[i][2] = qrow[32];
                qv[i][3] = qrow[48];
            }
            #pragma unroll
            for (int i = 0; i < 4; ++i) {
                float p = (acc[r][0][i] + bkc[0]) * qv[i][0]
                        + (acc[r][1][i] + bkc[1]) * qv[i][1]
                        + (acc[r][2][i] + bkc[2]) * qv[i][2]
                        + (acc[r][3][i] + bkc[3]) * qv[i][3];
                p += __shfl_xor(p, 1);
                p += __shfl_xor(p, 2);
                p += __shfl_xor(p, 4);
                p += __shfl_xor(p, 8);
                if (t16 == 0) {
                    const int el = r * 16 + qd * 4 + i;
                    const int ge = e0 + el;
                    if (ge < E) {
                        float sc = (p >= 0.f) ? p : LEAKY * p;
                        score[(size_t)spos[el] * 2 + w] = sc;
                    }
                }
            }
        }
    }
}

// ---------------------------------------------------------------------------
// Per-dst: softmax + weighted V sum + out-proj + ReLU + LN. V/score are in
// CSR order -> fully contiguous streams per dst (no elist gather).
// 512 threads = 16 dsts x 32 threads (4 cols each). WoutT staged via LDS.
// ---------------------------------------------------------------------------
__global__ __launch_bounds__(512) void k_dst(const unsigned short* __restrict__ V,
                                             const float* __restrict__ score,
                                             const int* __restrict__ offs,
                                             const float* __restrict__ h,
                                             const float* __restrict__ WT,
                                             const float* __restrict__ bout,
                                             const float* __restrict__ ln_w,
                                             const float* __restrict__ ln_b,
                                             float* __restrict__ out) {
    const int tid = threadIdx.x;
    const int s   = tid >> 5;        // sub 0..15
    const int t32 = tid & 31;
    const int d   = blockIdx.x * 16 + s;
    const bool valid = d < N_DST;
    const int beg = valid ? offs[d] : 0;
    const int end = valid ? offs[d + 1] : 0;

    __shared__ float inc[16][256];
    __shared__ float wchunk[64 * 128];

    // pass A: per-head max (contiguous float2 stream)
    float m0 = -1e30f, m1 = -1e30f;
    for (int i = beg + t32; i < end; i += 32) {
        float2 sc = *(const float2*)&score[(size_t)i * 2];
        m0 = fmaxf(m0, sc.x);
        m1 = fmaxf(m1, sc.y);
    }
    #pragma unroll
    for (int o = 1; o < 32; o <<= 1) {
        m0 = fmaxf(m0, __shfl_xor(m0, o));
        m1 = fmaxf(m1, __shfl_xor(m1, o));
    }
    const int   hd = t32 >> 4;
    const float mh = hd ? m1 : m0;

    // pass B: exp-weighted V accumulation — contiguous rows, 4-deep unroll
    float a0 = 0.f, a1 = 0.f, a2 = 0.f, a3 = 0.f, l = 0.f;
    int i = beg;
    for (; i + 3 < end; i += 4) {
        float s0 = score[(size_t)(i + 0) * 2 + hd];
        float s1 = score[(size_t)(i + 1) * 2 + hd];
        float s2 = score[(size_t)(i + 2) * 2 + hd];
        float s3 = score[(size_t)(i + 3) * 2 + hd];
        ushort4 v0 = *(const ushort4*)&V[(size_t)(i + 0) * DOUT + t32 * 4];
        ushort4 v1 = *(const ushort4*)&V[(size_t)(i + 1) * DOUT + t32 * 4];
        ushort4 v2 = *(const ushort4*)&V[(size_t)(i + 2) * DOUT + t32 * 4];
        ushort4 v3 = *(const ushort4*)&V[(size_t)(i + 3) * DOUT + t32 * 4];
        float w0 = __expf(s0 - mh);
        float w1 = __expf(s1 - mh);
        float w2 = __expf(s2 - mh);
        float w3 = __expf(s3 - mh);
        l += (w0 + w1) + (w2 + w3);
        a0 += w0 * bf2f(v0.x) + w1 * bf2f(v1.x) + w2 * bf2f(v2.x) + w3 * bf2f(v3.x);
        a1 += w0 * bf2f(v0.y) + w1 * bf2f(v1.y) + w2 * bf2f(v2.y) + w3 * bf2f(v3.y);
        a2 += w0 * bf2f(v0.z) + w1 * bf2f(v1.z) + w2 * bf2f(v2.z) + w3 * bf2f(v3.z);
        a3 += w0 * bf2f(v0.w) + w1 * bf2f(v1.w) + w2 * bf2f(v2.w) + w3 * bf2f(v3.w);
    }
    for (; i < end; ++i) {
        float s0 = score[(size_t)i * 2 + hd];
        ushort4 v0 = *(const ushort4*)&V[(size_t)i * DOUT + t32 * 4];
        float w0 = __expf(s0 - mh);
        l += w0;
        a0 += w0 * bf2f(v0.x);
        a1 += w0 * bf2f(v0.y);
        a2 += w0 * bf2f(v0.z);
        a3 += w0 * bf2f(v0.w);
    }
    float inv = (l > 0.f) ? (1.f / l) : 0.f;
    inc[s][t32 * 4 + 0] = a0 * inv;
    inc[s][t32 * 4 + 1] = a1 * inv;
    inc[s][t32 * 4 + 2] = a2 * inv;
    inc[s][t32 * 4 + 3] = a3 * inv;
    {
        float4 hh = make_float4(0.f, 0.f, 0.f, 0.f);
        if (valid) hh = *(const float4*)&h[(size_t)d * DN + t32 * 4];
        *(float4*)&inc[s][128 + t32 * 4] = hh;
    }

    // out-proj: r4 = bout + WoutT . inc, staged in 4 x 32KB LDS chunks
    float4 r4 = *(const float4*)&bout[t32 * 4];
    #pragma unroll 1
    for (int ch = 0; ch < 4; ++ch) {
        __syncthreads();
        for (int u = tid; u < 2048; u += 512)
            *(float4*)&wchunk[u * 4] = *(const float4*)&WT[(size_t)ch * 8192 + u * 4];
        __syncthreads();
        #pragma unroll 4
        for (int kk = 0; kk < 64; ++kk) {
            float ic = inc[s][ch * 64 + kk];
            float4 w4 = *(float4*)&wchunk[kk * 128 + t32 * 4];
            r4.x += w4.x * ic;
            r4.y += w4.y * ic;
            r4.z += w4.z * ic;
            r4.w += w4.w * ic;
        }
    }
    r4.x = fmaxf(r4.x, 0.f);
    r4.y = fmaxf(r4.y, 0.f);
    r4.z = fmaxf(r4.z, 0.f);
    r4.w = fmaxf(r4.w, 0.f);

    // LayerNorm over the dst's 128 cols (32 lanes x 4)
    float s1 = r4.x + r4.y + r4.z + r4.w;
    float s2 = r4.x * r4.x + r4.y * r4.y + r4.z * r4.z + r4.w * r4.w;
    #pragma unroll
    for (int o = 1; o < 32; o <<= 1) {
        s1 += __shfl_xor(s1, o);
        s2 += __shfl_xor(s2, o);
    }
    float mu  = s1 * (1.f / 128.f);
    float var = s2 * (1.f / 128.f) - mu * mu;
    float rsd = rsqrtf(var + LN_EPS);
    if (valid) {
        float4 lw = *(const float4*)&ln_w[t32 * 4];
        float4 lb = *(const float4*)&ln_b[t32 * 4];
        float4 o4;
        o4.x = (r4.x - mu) * rsd * lw.x + lb.x;
        o4.y = (r4.y - mu) * rsd * lw.y + lb.y;
        o4.z = (r4.z - mu) * rsd * lw.z + lb.z;
        o4.w = (r4.w - mu) * rsd * lw.w + lb.w;
        *(float4*)&out[(size_t)d * DOUT + t32 * 4] = o4;
    }
}

// ---------------------------------------------------------------------------
extern "C" void kernel_launch(void* const* d_in, const int* in_sizes, int n_in,
                              void* d_out, int out_size, void* d_ws, size_t ws_size,
                              hipStream_t stream) {
    const float* h       = (const float*)d_in[0];
    const float* f       = (const float*)d_in[1];
    const float* dt      = (const float*)d_in[2];
    const int*   src_idx = (const int*)d_in[3];
    const int*   dst_idx = (const int*)d_in[4];
    const float* w_t     = (const float*)d_in[5];
    const float* b_t     = (const float*)d_in[6];
    const float* Wq      = (const float*)d_in[7];
    const float* bq      = (const float*)d_in[8];
    const float* Wk      = (const float*)d_in[9];
    const float* bk      = (const float*)d_in[10];
    const float* Wv      = (const float*)d_in[11];
    const float* bv      = (const float*)d_in[12];
    const float* Wout    = (const float*)d_in[13];
    const float* bout    = (const float*)d_in[14];
    const float* ln_w    = (const float*)d_in[15];
    const float* ln_b    = (const float*)d_in[16];
    float*       out     = (float*)d_out;

    const int E = in_sizes[2];

    char* ws = (char*)d_ws;
    unsigned short* V  = (unsigned short*)(ws + OFF_V);
    float* score       = (float*)(ws + OFF_SCORE);
    float* qn          = (float*)(ws + OFF_QN);
    unsigned short* WS = (unsigned short*)(ws + OFF_WS);
    float* WT          = (float*)(ws + OFF_WT);
    int*   cnt         = (int*)(ws + OFF_CNT);
    int*   offs        = (int*)(ws + OFF_OFFS);
    int*   cursor      = (int*)(ws + OFF_CURSOR);
    int*   epos        = (int*)(ws + OFF_EPOS);

    hipMemsetAsync(cnt, 0, N_DST * sizeof(int), stream);

    k_prepw<<<256, 128, 0, stream>>>(Wk, Wv, WS);
    k_prepwt<<<256, 128, 0, stream>>>(Wout, WT);
    k_qnodes<<<(N_DST + 15) / 16, 256, 0, stream>>>(h, Wq, bq, b_t, qn);
    k_hist<<<(E + 255) / 256, 256, 0, stream>>>(dst_idx, cnt, E);
    k_scan<<<1, 256, 0, stream>>>(cnt, offs, cursor);
    k_scatter<<<(E + 255) / 256, 256, 0, stream>>>(dst_idx, cursor, epos, E);
    k_edge<<<(E + 63) / 64, 256, 0, stream>>>(h, f, dt, src_idx, dst_idx, epos,
                                              w_t, b_t, WS, bk, bv, qn, V, score, E);
    k_dst<<<(N_DST + 15) / 16, 512, 0, stream>>>(V, score, offs, h, WT, bout,
                                                 ln_w, ln_b, out);
}